// Round 16
// baseline (3359.612 us; speedup 1.0000x reference)
//
#include <hip/hip_runtime.h>

// PWC-Net cost volume, fp32. B=4, C=128, H=256, W=448, 81 shifts.
// out[b, di*9+dj, h, w] = (1/128) * sum_c feat1[b,c,h,w] * feat2[b,c,h+di-4,w+dj-4]
//
// Block = (b,h), 576 thr / 9 waves; wave w owns di = w (both halves of W).
// Lane owns 4 px per half: G = hf*56 + lane (56 active). Per channel one LDS
// buffer of 10 rows x 114 atoms(16B): rows 0..8 = feat2 h-4..h+4, row 9 =
// feat1 h. Atom a covers cols 4a-4..4a-1; atoms 0/113 = zero halo (zeroed
// once, never staged) -> edge semantics free, no store masking. Window for
// 9 dj at G = atoms G,G+1,G+2 -> 3 consecutive-per-lane ds_read_b128 =
// conflict-free (16-lane pass touches each bank exactly 2x). f1 = 1 b128.
// VMEM/CU drops to ~5.1K wave-instrs (3.6x less than the register family,
// which R14 proved is VMEM-instruction-bound).
//
// Ring-3 pipeline, drain-old counted vmcnt (fixes R1/R6 drain-young, R3/R7
// register blowups): body t: wait vmcnt(nIss) [= body t-1's issues, so
// stage(t) from body t-2 is done: ~2800 cy cover]; barrier; issue stage(t+2)
// [writes buf((t-1)%3), reads of which finished before this barrier]; 2 jobs
// of {4 ds_read_b128 + 36 FMA}. Tail bodies 126,127: vmcnt(0).
// Stage = 20 wave-issues (10 rows x 2 half-rows), wave-uniform LDS dest +
// lane*16 (global_load_lds constraint); OOB rows source 256 zeroed bytes of
// d_ws (uniform issue count). acc[2][9][4] = 72 regs; ~100 live total;
// __launch_bounds__(576,5) caps at 102 -> 2 blocks/CU (18 waves).

typedef __attribute__((ext_vector_type(4))) float f32x4;

#define GLAS(p) ((const __attribute__((address_space(1))) unsigned int*)(p))
#define LDAS(p) ((__attribute__((address_space(3))) unsigned int*)(p))

__global__ __launch_bounds__(576, 5) void cv_kernel(
    const float* __restrict__ feat1,
    const float* __restrict__ feat2,
    const float* __restrict__ zws,
    float* __restrict__ out)
{
    constexpr int C = 128, H = 256, W = 448;
    constexpr size_t HW = (size_t)H * W;
    constexpr int ROWB = 114 * 16;     // 1824 B
    constexpr int BUFB = 10 * ROWB;    // 18240 B
    __shared__ __align__(16) char f2s[3 * BUFB];   // 54720 B

    const int tid  = threadIdx.x;
    const int wid  = tid >> 6;         // 0..8 == di
    const int lane = tid & 63;
    const int m    = (lane < 56) ? lane : 55;

    // XCD-contiguous (b,h) mapping (1024 = 8*128, bijective)
    const int lin = (blockIdx.x & 7) * 128 + (blockIdx.x >> 3);
    const int b = lin >> 8, h = lin & 255;

    // Zero all LDS once: halo atoms 0/113 and nothing else matters after
    // staging overwrites atoms 1..112 every body; OOB rows stage from zws.
    for (int i = tid; i < (int)sizeof(f2s) / 16; i += 576)
        *(f32x4*)(f2s + i * 16) = (f32x4){0.f, 0.f, 0.f, 0.f};

    // Staging descriptors: issues j = wid, wid+9, (wid+18 if wid<2).
    // Issue j: row r = j/2 (0..9), half = j&1. Lanes 0..55 load 16B from
    // src_row + (half*224 + lane*4) floats -> dest r*1824 + 16 + half*896 + lane*16.
    const int nIss = (wid < 2) ? 3 : 2;
    const float* sp[3]; size_t sstep[3]; int sdst[3];
#pragma unroll
    for (int k = 0; k < 3; ++k) {
        if (k < nIss) {
            const int j = wid + 9 * k;
            const int r = j >> 1, hf = j & 1;
            const int colf = hf * 224 + ((lane < 56) ? lane * 4 : 220);
            bool ok;
            const float* base;
            if (r == 9) { ok = true;  base = feat1 + ((size_t)b * C * H + (size_t)h) * W + colf; }
            else {
                const int hr = h + r - 4;
                ok = (hr >= 0) && (hr < H);
                base = ok ? (feat2 + ((size_t)b * C * H + (size_t)hr) * W + colf) : zws;
            }
            sp[k] = base; sstep[k] = ok ? HW : 0;
            sdst[k] = r * ROWB + 16 + hf * 896;
        }
    }

    // Job read offsets (row wid for f2, row 9 for f1), per half hf:
    // f2 atoms G..G+2 at bytes 16G,+16,+32; f1 atom G+1.
    const int G0 = m, G1 = 56 + m;
    const int r2o0 = wid * ROWB + G0 * 16;
    const int r2o1 = wid * ROWB + G1 * 16;
    const int r1o0 = 9 * ROWB + (G0 + 1) * 16;
    const int r1o1 = 9 * ROWB + (G1 + 1) * 16;

    float acc[2][9][4];
#pragma unroll
    for (int hf = 0; hf < 2; ++hf)
#pragma unroll
        for (int j = 0; j < 9; ++j)
#pragma unroll
            for (int p = 0; p < 4; ++p) acc[hf][j][p] = 0.0f;

    __syncthreads();   // LDS zeros visible before first stage lands

#define STAGE(BUFOFS) do { \
    _Pragma("unroll") \
    for (int k = 0; k < 3; ++k) { \
        if (k < nIss) { \
            if (lane < 56) \
                __builtin_amdgcn_global_load_lds(GLAS(sp[k]), \
                    LDAS(f2s + (BUFOFS) + sdst[k]), 16, 0, 0); \
            sp[k] += sstep[k]; \
        } \
    } } while (0)

#define JOB(BUFOFS, R2O, R1O, HF) do { \
    const char* lb = f2s + (BUFOFS); \
    const f32x4 L = *(const f32x4*)(lb + (R2O)); \
    const f32x4 Cq = *(const f32x4*)(lb + (R2O) + 16); \
    const f32x4 R = *(const f32x4*)(lb + (R2O) + 32); \
    const f32x4 A = *(const f32x4*)(lb + (R1O)); \
    const float w[12] = {L.x, L.y, L.z, L.w, Cq.x, Cq.y, Cq.z, Cq.w, \
                         R.x, R.y, R.z, R.w}; \
    const float a[4] = {A.x, A.y, A.z, A.w}; \
    _Pragma("unroll") \
    for (int dj = 0; dj < 9; ++dj) { \
        _Pragma("unroll") \
        for (int p = 0; p < 4; ++p) \
            acc[HF][dj][p] = fmaf(a[p], w[dj + p], acc[HF][dj][p]); \
    } } while (0)

#define BODY(BUF, NBUF, MODE) do { \
    if ((MODE) == 0) { \
        if (wid < 2) asm volatile("s_waitcnt vmcnt(3)" ::: "memory"); \
        else         asm volatile("s_waitcnt vmcnt(2)" ::: "memory"); \
    } else { \
        asm volatile("s_waitcnt vmcnt(0)" ::: "memory"); \
    } \
    __builtin_amdgcn_s_barrier(); \
    __builtin_amdgcn_sched_barrier(0); \
    if ((MODE) == 0) STAGE((NBUF) * BUFB); \
    JOB((BUF) * BUFB, r2o0, r1o0, 0); \
    JOB((BUF) * BUFB, r2o1, r1o1, 1); \
  } while (0)

    // Prologue: stage bundles 0,1 into buffers 0,1.
    STAGE(0 * BUFB);
    STAGE(1 * BUFB);

    // Bodies t = 0..125 (42 x 3): body t stages t+2 into buf (t+2)%3.
    for (int g = 0; g < 42; ++g) {
        BODY(0, 2, 0);
        BODY(1, 0, 0);
        BODY(2, 1, 0);
    }
    BODY(0, 2, 1);   // t = 126
    BODY(1, 0, 1);   // t = 127

#undef STAGE
#undef JOB
#undef BODY

    if (lane < 56) {
        const float s = 1.0f / 128.0f;
#pragma unroll
        for (int hf = 0; hf < 2; ++hf) {
            const int G = hf * 56 + m;
            float* ob = out + (((size_t)(b * 81 + wid * 9)) * H + h) * W + G * 4;
#pragma unroll
            for (int dj = 0; dj < 9; ++dj) {
                f32x4 ov = {acc[hf][dj][0] * s, acc[hf][dj][1] * s,
                            acc[hf][dj][2] * s, acc[hf][dj][3] * s};
                *(f32x4*)(ob + (size_t)dj * HW) = ov;
            }
        }
    }
}

extern "C" void kernel_launch(void* const* d_in, const int* in_sizes, int n_in,
                              void* d_out, int out_size, void* d_ws, size_t ws_size,
                              hipStream_t stream) {
    const float* feat1 = (const float*)d_in[0];
    const float* feat2 = (const float*)d_in[1];
    float* out = (float*)d_out;
    // 256 zeroed bytes: stage source for vertically-OOB feat2 rows.
    hipMemsetAsync(d_ws, 0, 256, stream);
    cv_kernel<<<dim3(1024), dim3(576), 0, stream>>>(
        feat1, feat2, (const float*)d_ws, out);
}

// Round 17
// 277.830 us; speedup vs baseline: 12.0923x; 12.0923x over previous
//
#include <hip/hip_runtime.h>

// PWC-Net cost volume, fp32. B=4, C=128, H=256, W=448, 81 shifts.
// out[b, di*9+dj, h, w] = (1/128) * sum_c feat1[b,c,h,w] * feat2[b,c,h+di-4,w+dj-4]
//
// Block = (b,h), 1024 thr / 16 waves. Thread owns ONE 4-px quad:
// it = tid -> di = it/112, G = it%112 (1008 active). acc[9][4] = 36 regs;
// total demand ~75 << cap 128 (launch_bounds(1024,4)) -> NO spill (R7/R9/R15
// all died from cap < demand).
//
// Per channel one LDS buffer: 10 rows x 114 atoms(16B). Rows 0..8 = feat2
// h-4..h+4 (OOB rows staged as zeros from zws every body -> no masking, no
// divergent exits), row 9 = feat1 h. Atom a covers cols 4a-4..4a-1; atoms
// 0/113 = halo, zeroed once, never staged. Window for 9 dj at quad G =
// atoms G,G+1,G+2 (lane-stride-1 -> 2-way bank aliasing, free); f1 = atom
// G+1 of row 9. 4 ds_read_b128 + 36 FMA per thread-body.
//
// Ring-3 pipeline, drain-old counted vmcnt: body t waits vmcnt(nIss)
// (drains bundle t, issued 2 bodies ago; bundle t+1 stays in flight),
// barrier, stages bundle t+2 into buf (t+2)%3, computes buf t%3.
// Stage = 20 issues (10 rows x 2 half-rows): wave wid takes j = wid and
// (16+wid if wid<4); nIss = 2 (wid<4) else 1. global_load_lds: LDS dest
// wave-uniform+lane*16 (linear), per-lane global source.

typedef __attribute__((ext_vector_type(4))) float f32x4;

#define GLAS(p) ((const __attribute__((address_space(1))) unsigned int*)(p))
#define LDAS(p) ((__attribute__((address_space(3))) unsigned int*)(p))

__global__ __launch_bounds__(1024, 4) void cv_kernel(
    const float* __restrict__ feat1,
    const float* __restrict__ feat2,
    const float* __restrict__ zws,
    float* __restrict__ out)
{
    constexpr int C = 128, H = 256, W = 448;
    constexpr size_t HW = (size_t)H * W;
    constexpr int ROWB = 114 * 16;     // 1824 B
    constexpr int BUFB = 10 * ROWB;    // 18240 B
    __shared__ __align__(16) char f2s[3 * BUFB];   // 54720 B

    const int tid  = threadIdx.x;
    const int wid  = tid >> 6;
    const int lane = tid & 63;

    // XCD-contiguous (b,h) mapping (1024 = 8*128, bijective)
    const int lin = (blockIdx.x & 7) * 128 + (blockIdx.x >> 3);
    const int b = lin >> 8, h = lin & 255;

    const int it = (tid < 1008) ? tid : 1007;
    const int di = it / 112;
    const int G  = it - di * 112;      // 0..111

    // Zero LDS once (halo atoms 0/113 persist; staged atoms overwritten).
    for (int i = tid; i < (int)sizeof(f2s) / 16; i += 1024)
        *(f32x4*)(f2s + i * 16) = (f32x4){0.f, 0.f, 0.f, 0.f};

    // Staging descriptors. Issue j: row r = j>>1 (0..9), half hf = j&1.
    // Lanes 0..55: 16B from row_base + hf*224 + lane*4 floats
    //   -> dest r*ROWB + 16 + hf*896 + lane*16 (atoms 1..112 linear).
    // r==9 -> feat1 row h; else feat2 row h+r-4 (OOB -> zws, step 0).
    const int nIss = (wid < 4) ? 2 : 1;
    const float* sp[2]; unsigned sstep[2]; int sdst[2];
#pragma unroll
    for (int k = 0; k < 2; ++k) {
        if (k < nIss) {
            const int j  = wid + 16 * k;
            const int r  = j >> 1, hf = j & 1;
            const int colf = hf * 224 + ((lane < 56) ? lane * 4 : 220);
            if (r == 9) {
                sp[k] = feat1 + ((size_t)b * C * H + (size_t)h) * W + colf;
                sstep[k] = (unsigned)HW;
            } else {
                const int hr = h + r - 4;
                const bool ok = (hr >= 0) && (hr < H);
                sp[k] = ok ? (feat2 + ((size_t)b * C * H + (size_t)hr) * W + colf) : zws;
                sstep[k] = ok ? (unsigned)HW : 0u;
            }
            sdst[k] = r * ROWB + 16 + hf * 896;
        }
    }

    // Read offsets: f2 atoms G..G+2 of row di; f1 atom G+1 of row 9.
    const int r2o = di * ROWB + G * 16;
    const int r1o = 9 * ROWB + (G + 1) * 16;

    float acc[9][4];
#pragma unroll
    for (int j = 0; j < 9; ++j)
#pragma unroll
        for (int p = 0; p < 4; ++p) acc[j][p] = 0.0f;

    __syncthreads();   // LDS zeros visible before first stage lands

#define STAGE(BUFOFS) do { \
    _Pragma("unroll") \
    for (int k = 0; k < 2; ++k) { \
        if (k < nIss) { \
            if (lane < 56) \
                __builtin_amdgcn_global_load_lds(GLAS(sp[k]), \
                    LDAS(f2s + (BUFOFS) + sdst[k]), 16, 0, 0); \
            sp[k] += sstep[k]; \
        } \
    } } while (0)

#define BODY(BUF, NBUF, MODE) do { \
    if ((MODE) <= 1) { \
        if (wid < 4) asm volatile("s_waitcnt vmcnt(2)" ::: "memory"); \
        else         asm volatile("s_waitcnt vmcnt(1)" ::: "memory"); \
    } else { \
        asm volatile("s_waitcnt vmcnt(0)" ::: "memory"); \
    } \
    __builtin_amdgcn_s_barrier(); \
    __builtin_amdgcn_sched_barrier(0); \
    if ((MODE) == 0) STAGE((NBUF) * BUFB); \
    { \
        const char* lb = f2s + (BUF) * BUFB; \
        const f32x4 L  = *(const f32x4*)(lb + r2o); \
        const f32x4 Cq = *(const f32x4*)(lb + r2o + 16); \
        const f32x4 R  = *(const f32x4*)(lb + r2o + 32); \
        const f32x4 A  = *(const f32x4*)(lb + r1o); \
        const float w[12] = {L.x, L.y, L.z, L.w, Cq.x, Cq.y, Cq.z, Cq.w, \
                             R.x, R.y, R.z, R.w}; \
        const float a[4] = {A.x, A.y, A.z, A.w}; \
        _Pragma("unroll") \
        for (int dj = 0; dj < 9; ++dj) { \
            _Pragma("unroll") \
            for (int p = 0; p < 4; ++p) \
                acc[dj][p] = fmaf(a[p], w[dj + p], acc[dj][p]); \
        } \
    } } while (0)

    // Prologue: bundles 0,1 into buffers 0,1.
    STAGE(0 * BUFB);
    STAGE(1 * BUFB);

    // Bodies 0..125: stage t+2. Tail: 126 (wait main), 127 (wait 0).
#pragma unroll 1
    for (int g = 0; g < 42; ++g) {
        BODY(0, 2, 0);
        BODY(1, 0, 0);
        BODY(2, 1, 0);
    }
    BODY(0, 2, 1);   // t = 126
    BODY(1, 0, 2);   // t = 127

#undef STAGE
#undef BODY

    if (tid < 1008) {
        const float s = 1.0f / 128.0f;
        float* ob = out + (((size_t)(b * 81 + di * 9)) * H + h) * W + G * 4;
#pragma unroll
        for (int dj = 0; dj < 9; ++dj) {
            f32x4 ov = {acc[dj][0] * s, acc[dj][1] * s,
                        acc[dj][2] * s, acc[dj][3] * s};
            *(f32x4*)(ob + (size_t)dj * HW) = ov;
        }
    }
}

extern "C" void kernel_launch(void* const* d_in, const int* in_sizes, int n_in,
                              void* d_out, int out_size, void* d_ws, size_t ws_size,
                              hipStream_t stream) {
    const float* feat1 = (const float*)d_in[0];
    const float* feat2 = (const float*)d_in[1];
    float* out = (float*)d_out;
    // 256 zeroed bytes: broadcast-source for vertically-OOB feat2 rows.
    hipMemsetAsync(d_ws, 0, 256, stream);
    cv_kernel<<<dim3(1024), dim3(1024), 0, stream>>>(
        feat1, feat2, (const float*)d_ws, out);
}